// Round 4
// baseline (348.307 us; speedup 1.0000x reference)
//
#include <hip/hip_runtime.h>
#include <stdint.h>
#include <math.h>

#define NB 4
#define NN 4096
#define NF 256
#define ND 128
#define QB 64            // q rows per attn block (4 waves x 16 rows)
#define KVB 32           // kv rows per tile
#define NR (NB * NN)

typedef __bf16 bf16x8 __attribute__((ext_vector_type(8)));
typedef float f32x4 __attribute__((ext_vector_type(4)));
typedef unsigned short u16x8 __attribute__((ext_vector_type(8)));
typedef unsigned short u16x4 __attribute__((ext_vector_type(4)));

__device__ __forceinline__ unsigned short f2bf(float f) {
    union { float f; uint32_t u; } v; v.f = f;
    uint32_t r = (v.u + 0x7FFFu + ((v.u >> 16) & 1u)) >> 16;
    return (unsigned short)r;
}

__device__ __forceinline__ bf16x8 lds_read16(const unsigned short* base, int byte_off) {
    return *reinterpret_cast<const bf16x8*>(reinterpret_cast<const char*>(base) + byte_off);
}

__device__ __forceinline__ void gld_lds16(const void* g, void* l) {
    __builtin_amdgcn_global_load_lds(
        (const __attribute__((address_space(1))) void*)g,
        (__attribute__((address_space(3))) void*)l, 16, 0, 0);
}

// ---------------- Kernel 1: QKV projection (bf16 MFMA, f32 acc) ----------------
// grid (256, 3): x = 64-row tile of B*N, y = projection (0=Q,1=K,2=V).
// Q pre-scaled by 1/sqrt(128). V written in attn-LDS tile order:
//   VS[b][tile(128)][chunk(4)][d(128)][m8] bf16  (tile=32 m-rows, chunk=8 m's)
__global__ __launch_bounds__(256) void qkv_proj(
    const float* __restrict__ h,
    const float* __restrict__ Wq, const float* __restrict__ bq,
    const float* __restrict__ Wk, const float* __restrict__ bk,
    const float* __restrict__ Wv, const float* __restrict__ bv,
    unsigned short* __restrict__ qo, unsigned short* __restrict__ ko,
    unsigned short* __restrict__ vs, float qscale)
{
    __shared__ unsigned short h_lds[64 * 128];
    __shared__ unsigned short w_lds[128 * 128];

    const int tid = threadIdx.x;
    const int lane = tid & 63;
    const int wv = tid >> 6;
    const int l15 = lane & 15;
    const int lhi = lane >> 4;
    const int R0 = blockIdx.x * 64;
    const int proj = blockIdx.y;

    const float* W    = proj == 0 ? Wq : (proj == 1 ? Wk : Wv);
    const float* bias = proj == 0 ? bq : (proj == 1 ? bk : bv);
    const float scale = proj == 0 ? qscale : 1.0f;

    f32x4 acc[8];
#pragma unroll
    for (int i = 0; i < 8; ++i) acc[i] = f32x4{0.f, 0.f, 0.f, 0.f};

    for (int kc = 0; kc < 2; ++kc) {
        const int c0 = kc * 128;
        __syncthreads();
#pragma unroll
        for (int p = 0; p < 8; ++p) {
            int idx = p * 256 + tid;
            int row = idx >> 5;
            int seg = idx & 31;
            f32x4 hv = *reinterpret_cast<const f32x4*>(h + (size_t)(R0 + row) * NF + c0 + seg * 4);
            u16x4 hb;
            hb[0] = f2bf(hv[0]); hb[1] = f2bf(hv[1]); hb[2] = f2bf(hv[2]); hb[3] = f2bf(hv[3]);
            int byte = (row * 256 + seg * 8) ^ ((row & 7) << 4);
            *reinterpret_cast<u16x4*>(reinterpret_cast<char*>(h_lds) + byte) = hb;
        }
#pragma unroll
        for (int p = 0; p < 16; ++p) {
            int idx = p * 256 + tid;
            int row = idx >> 5;
            int seg = idx & 31;
            f32x4 wv4 = *reinterpret_cast<const f32x4*>(W + (size_t)row * NF + c0 + seg * 4);
            u16x4 wb;
            wb[0] = f2bf(wv4[0]); wb[1] = f2bf(wv4[1]); wb[2] = f2bf(wv4[2]); wb[3] = f2bf(wv4[3]);
            int byte = (row * 256 + seg * 8) ^ ((row & 7) << 4);
            *reinterpret_cast<u16x4*>(reinterpret_cast<char*>(w_lds) + byte) = wb;
        }
        __syncthreads();
        const int arow = 16 * wv + l15;
#pragma unroll
        for (int ks = 0; ks < 4; ++ks) {
            int k = ks * 32 + 8 * lhi;
            bf16x8 a = lds_read16(h_lds, (arow * 256 + k * 2) ^ ((arow & 7) << 4));
#pragma unroll
            for (int cs = 0; cs < 8; ++cs) {
                int d = 16 * cs + l15;
                bf16x8 b = lds_read16(w_lds, (d * 256 + k * 2) ^ ((d & 7) << 4));
                acc[cs] = __builtin_amdgcn_mfma_f32_16x16x32_bf16(a, b, acc[cs], 0, 0, 0);
            }
        }
    }
    if (proj < 2) {
        unsigned short* out = proj == 0 ? qo : ko;
#pragma unroll
        for (int cs = 0; cs < 8; ++cs) {
            int d = 16 * cs + l15;
            float bb = bias[d];
#pragma unroll
            for (int j = 0; j < 4; ++j) {
                int row = R0 + 16 * wv + 4 * lhi + j;
                out[(size_t)row * ND + d] = f2bf((acc[cs][j] + bb) * scale);
            }
        }
    } else {
        // V in attn-tile layout
        const int bb_ = R0 >> 12;
        const int nb_ = (R0 & (NN - 1)) + 16 * wv + 4 * lhi;
        const int pt = nb_ >> 5;
        const int ch = (nb_ >> 3) & 3;
        const int mm0 = nb_ & 7;
#pragma unroll
        for (int cs = 0; cs < 8; ++cs) {
            int d = 16 * cs + l15;
            float bb = bias[d];
            u16x4 o;
#pragma unroll
            for (int j = 0; j < 4; ++j) o[j] = f2bf(acc[cs][j] + bb);
            size_t idx = ((size_t)(bb_ * 128 + pt)) * 4096 + ch * 1024 + d * 8 + mm0;
            *reinterpret_cast<u16x4*>(vs + idx) = o;
        }
    }
}

// ---------------- Kernel 2: fused masked flash attention (KV-split) ----------------
// 256 threads = 4 waves; wave w owns q rows q0+16w..+15. KVB=32 double-buffered.
// LDS 36 KB -> 4 blocks/CU x 4 waves = 16 waves/CU.
__global__ __launch_bounds__(256, 4) void attn(
    const unsigned short* __restrict__ Q,   // [B*N,128] bf16, pre-scaled
    const unsigned short* __restrict__ K,   // [B*N,128] bf16
    const unsigned short* __restrict__ VS,  // tiled V (see proj)
    const int* __restrict__ adj,            // [B,N,N] i32
    float* __restrict__ out,                // split-0 partial O storage (and final out)
    float* __restrict__ opart1,             // splits 1.. partial O
    float* __restrict__ ml,                 // [nsplit][NR][2] f32 (m, l)
    int ntl)                                // tiles per split
{
    __shared__ unsigned short kA[KVB * 128], kB[KVB * 128];   // 8 KB each
    __shared__ unsigned short vA[4096], vB[4096];             // 8 KB each (tiled layout)
    __shared__ unsigned short p_lds[4 * 512];                 // per-wave 16x32 P tile

    const int tid = threadIdx.x;
    const int lane = tid & 63;
    const int w = tid >> 6;
    const int l15 = lane & 15;
    const int lhi = lane >> 4;

    // XCD-grouped decode: flat = s*512 + qt*8 + x ; combo = x + 8s -> (b, sp)
    const int flat = blockIdx.x;
    const int x = flat & 7;
    const int qt = (flat >> 3) & 63;
    const int s_ = flat >> 9;
    const int combo = x + 8 * s_;
    const int b = combo & 3;
    const int sp = combo >> 2;
    const int q0 = qt * QB;
    const size_t bN = (size_t)b * NN;
    const size_t abase = (size_t)b * NN * NN;
    const int ptbase = sp * ntl;

    auto stage = [&](unsigned short* kb, unsigned short* vb, int pt) {
        const int m0 = pt * KVB;
#pragma unroll
        for (int i = 0; i < 2; ++i) {
            int slot = w * 2 + i;                      // 0..7, 1 KB slots
            int row = slot * 4 + (lane >> 4);
            int pc = lane & 15;
            int lc = pc ^ (row & 7);
            gld_lds16(K + (bN + m0 + row) * ND + lc * 8, kb + slot * 512);
        }
        const unsigned short* vsrc = VS + ((size_t)(b * 128 + pt)) * 4096;
#pragma unroll
        for (int i = 0; i < 2; ++i) {
            int slot = w * 2 + i;
            gld_lds16(vsrc + slot * 512 + lane * 8, vb + slot * 512);
        }
    };
    auto adj_load = [&](int (&ar)[8], int pt) {
        const int m0 = pt * KVB;
#pragma unroll
        for (int ms = 0; ms < 2; ++ms)
#pragma unroll
            for (int j = 0; j < 4; ++j) {
                int r = 16 * w + 4 * lhi + j;
                int c = 16 * ms + l15;
                ar[ms * 4 + j] = adj[abase + (size_t)(q0 + r) * NN + m0 + c];
            }
    };

    int aregA[8], aregB[8];
    stage(kA, vA, ptbase);
    adj_load(aregA, ptbase);

    bf16x8 qf[4];
#pragma unroll
    for (int ks = 0; ks < 4; ++ks)
        qf[ks] = *reinterpret_cast<const bf16x8*>(Q + (bN + q0 + 16 * w + l15) * ND + ks * 32 + 8 * lhi);

    f32x4 acc_o[8];
#pragma unroll
    for (int i = 0; i < 8; ++i) acc_o[i] = f32x4{0.f, 0.f, 0.f, 0.f};
    float m_run[4], l_run[4];
#pragma unroll
    for (int j = 0; j < 4; ++j) { m_run[j] = -INFINITY; l_run[j] = 0.f; }

    auto body = [&](unsigned short* kc, unsigned short* vc, const int (&ac)[8],
                    unsigned short* kn, unsigned short* vn, int (&an)[8], int t) {
        int tn = (t + 1 < ntl) ? t + 1 : ntl - 1;
        stage(kn, vn, ptbase + tn);
        adj_load(an, ptbase + tn);
        // wait for CURRENT tile (12 per-wave VMEM ops/iter stay in flight)
        asm volatile("s_waitcnt vmcnt(12)" ::: "memory");
        __builtin_amdgcn_s_barrier();
        __builtin_amdgcn_sched_barrier(0);

        // ---- S = Q K^T  (32 m-cols = 2 subtiles)
        f32x4 s[2];
        __builtin_amdgcn_s_setprio(1);
#pragma unroll
        for (int ms = 0; ms < 2; ++ms) {
            s[ms] = f32x4{0.f, 0.f, 0.f, 0.f};
#pragma unroll
            for (int ks = 0; ks < 4; ++ks) {
                int mrow = 16 * ms + l15;
                bf16x8 bf = lds_read16(kc, (mrow * 256 + ks * 64 + lhi * 16) ^ ((mrow & 7) << 4));
                s[ms] = __builtin_amdgcn_mfma_f32_16x16x32_bf16(qf[ks], bf, s[ms], 0, 0, 0);
            }
        }
        __builtin_amdgcn_s_setprio(0);
        // ---- mask
#pragma unroll
        for (int ms = 0; ms < 2; ++ms)
#pragma unroll
            for (int j = 0; j < 4; ++j)
                if (ac[ms * 4 + j] == 0) s[ms][j] = -9e15f;
        // ---- online softmax
        float mnew[4], corr[4];
#pragma unroll
        for (int j = 0; j < 4; ++j) {
            float mx = fmaxf(s[0][j], s[1][j]);
#pragma unroll
            for (int off = 1; off < 16; off <<= 1)
                mx = fmaxf(mx, __shfl_xor(mx, off, 64));
            mnew[j] = fmaxf(m_run[j], mx);
            corr[j] = __expf(m_run[j] - mnew[j]);
            m_run[j] = mnew[j];
        }
        float rsum[4] = {0.f, 0.f, 0.f, 0.f};
        unsigned short pb[2][4];
#pragma unroll
        for (int ms = 0; ms < 2; ++ms)
#pragma unroll
            for (int j = 0; j < 4; ++j) {
                float p = __expf(s[ms][j] - mnew[j]);
                rsum[j] += p;
                pb[ms][j] = f2bf(p);
            }
#pragma unroll
        for (int j = 0; j < 4; ++j) {
            float rs = rsum[j];
#pragma unroll
            for (int off = 1; off < 16; off <<= 1)
                rs += __shfl_xor(rs, off, 64);
            l_run[j] = l_run[j] * corr[j] + rs;
#pragma unroll
            for (int ds = 0; ds < 8; ++ds) acc_o[ds][j] *= corr[j];
        }
        // ---- P -> per-wave LDS tile [16 q][32 m], 64B rows, (r&7)<<4 swizzle
#pragma unroll
        for (int ms = 0; ms < 2; ++ms)
#pragma unroll
            for (int j = 0; j < 4; ++j) {
                int r = 4 * lhi + j;
                int c = 16 * ms + l15;
                int byte = w * 1024 + ((r * 64 + c * 2) ^ ((r & 7) << 4));
                *reinterpret_cast<unsigned short*>(reinterpret_cast<char*>(p_lds) + byte) = pb[ms][j];
            }
        // ---- PV: acc_o += P @ V   (single 32-k window)
        {
            bf16x8 pa = lds_read16(p_lds, w * 1024 + ((l15 * 64 + lhi * 16) ^ ((l15 & 7) << 4)));
            __builtin_amdgcn_s_setprio(1);
#pragma unroll
            for (int ds = 0; ds < 8; ++ds) {
                int d = 16 * ds + l15;
                bf16x8 vbf = lds_read16(vc, lhi * 2048 + d * 16);
                acc_o[ds] = __builtin_amdgcn_mfma_f32_16x16x32_bf16(pa, vbf, acc_o[ds], 0, 0, 0);
            }
            __builtin_amdgcn_s_setprio(0);
        }
        asm volatile("s_waitcnt lgkmcnt(0)" ::: "memory");
        __builtin_amdgcn_sched_barrier(0);
        __builtin_amdgcn_s_barrier();
        __builtin_amdgcn_sched_barrier(0);
    };

    for (int t = 0; t < ntl; t += 2) {
        body(kA, vA, aregA, kB, vB, aregB, t);
        body(kB, vB, aregB, kA, vA, aregA, t + 1);
    }

    // ---- epilogue: store partial O (unnormalized) + (m, l)
    float* op = (sp == 0) ? out : (opart1 + (size_t)(sp - 1) * NR * ND);
#pragma unroll
    for (int ds = 0; ds < 8; ++ds) {
        int d = 16 * ds + l15;
#pragma unroll
        for (int j = 0; j < 4; ++j) {
            int row = q0 + 16 * w + 4 * lhi + j;
            op[(bN + row) * ND + d] = acc_o[ds][j];
        }
    }
    if (l15 == 0) {
#pragma unroll
        for (int j = 0; j < 4; ++j) {
            size_t gr = bN + q0 + 16 * w + 4 * lhi + j;
            float2 v2 = make_float2(m_run[j], l_run[j]);
            *reinterpret_cast<float2*>(ml + ((size_t)sp * NR + gr) * 2) = v2;
        }
    }
}

// ---------------- Kernel 3: merge the KV-splits (in-place on out) ----------------
__global__ __launch_bounds__(256) void merge_splits(
    float* __restrict__ out, const float* __restrict__ opart1,
    const float* __restrict__ ml, int nsplit)
{
    int idx = blockIdx.x * 256 + threadIdx.x;   // 0 .. NR*32-1
    int row = idx >> 5;
    int d4 = (idx & 31) * 4;
    float mmax = ml[(size_t)row * 2];
    for (int sp = 1; sp < nsplit; ++sp)
        mmax = fmaxf(mmax, ml[((size_t)sp * NR + row) * 2]);
    f32x4 o0 = *reinterpret_cast<const f32x4*>(out + (size_t)row * ND + d4);
    float w0 = __expf(ml[(size_t)row * 2] - mmax);
    float lsum = ml[(size_t)row * 2 + 1] * w0;
    f32x4 acc;
#pragma unroll
    for (int j = 0; j < 4; ++j) acc[j] = o0[j] * w0;
    for (int sp = 1; sp < nsplit; ++sp) {
        float m_s = ml[((size_t)sp * NR + row) * 2];
        float l_s = ml[((size_t)sp * NR + row) * 2 + 1];
        float ws_ = __expf(m_s - mmax);
        f32x4 os = *reinterpret_cast<const f32x4*>(opart1 + ((size_t)(sp - 1) * NR + row) * ND + d4);
#pragma unroll
        for (int j = 0; j < 4; ++j) acc[j] += os[j] * ws_;
        lsum += l_s * ws_;
    }
    float inv = 1.0f / lsum;
    f32x4 r;
#pragma unroll
    for (int j = 0; j < 4; ++j) r[j] = acc[j] * inv;
    *reinterpret_cast<f32x4*>(out + (size_t)row * ND + d4) = r;
}

extern "C" void kernel_launch(void* const* d_in, const int* in_sizes, int n_in,
                              void* d_out, int out_size, void* d_ws, size_t ws_size,
                              hipStream_t stream) {
    const float* h  = (const float*)d_in[0];
    const int* adj  = (const int*)d_in[1];
    const float* Wq = (const float*)d_in[2];
    const float* bq = (const float*)d_in[3];
    const float* Wk = (const float*)d_in[4];
    const float* bk = (const float*)d_in[5];
    const float* Wv = (const float*)d_in[6];
    const float* bv = (const float*)d_in[7];
    float* out = (float*)d_out;

    const size_t qkv_elems = (size_t)NB * NN * ND;      // 2,097,152 bf16 each
    unsigned short* qws  = (unsigned short*)d_ws;
    unsigned short* kws  = qws + qkv_elems;
    unsigned short* vsws = kws + qkv_elems;
    float* opart1 = (float*)(vsws + qkv_elems);

    // nsplit=4 needs 12.58MB (qkv) + 3*8.39MB (partials) + 0.52MB (ml)
    const size_t need4 = 3 * qkv_elems * 2 + 3 * (size_t)NR * ND * 4 + 4 * (size_t)NR * 2 * 4;
    const int nsplit = (ws_size >= need4) ? 4 : 2;
    float* mlws = opart1 + (size_t)(nsplit - 1) * NR * ND;
    const int ntl = (NN / KVB) / nsplit;                // 32 or 64

    const float qscale = 0.08838834764831845f;  // 1/sqrt(128)

    qkv_proj<<<dim3(NB * NN / 64, 3), 256, 0, stream>>>(
        h, Wq, bq, Wk, bk, Wv, bv, qws, kws, vsws, qscale);
    attn<<<dim3(NB * (NN / QB) * nsplit), 256, 0, stream>>>(
        qws, kws, vsws, adj, out, opart1, mlws, ntl);
    merge_splits<<<dim3(NR * 32 / 256), 256, 0, stream>>>(out, opart1, mlws, nsplit);
}

// Round 5
// 169.623 us; speedup vs baseline: 2.0534x; 2.0534x over previous
//
#include <hip/hip_runtime.h>
#include <stdint.h>
#include <math.h>

#define NB 4
#define NN 4096
#define NF 256
#define ND 128
#define QB 64            // q rows per attn block (4 waves x 16 rows)
#define KVB 32           // kv rows per tile
#define NR (NB * NN)

typedef __bf16 bf16x8 __attribute__((ext_vector_type(8)));
typedef float f32x4 __attribute__((ext_vector_type(4)));
typedef unsigned short u16x8 __attribute__((ext_vector_type(8)));
typedef unsigned short u16x4 __attribute__((ext_vector_type(4)));

__device__ __forceinline__ unsigned short f2bf(float f) {
    union { float f; uint32_t u; } v; v.f = f;
    uint32_t r = (v.u + 0x7FFFu + ((v.u >> 16) & 1u)) >> 16;
    return (unsigned short)r;
}

__device__ __forceinline__ bf16x8 lds_read16(const unsigned short* base, int byte_off) {
    return *reinterpret_cast<const bf16x8*>(reinterpret_cast<const char*>(base) + byte_off);
}

__device__ __forceinline__ void gld_lds16(const void* g, void* l) {
    __builtin_amdgcn_global_load_lds(
        (const __attribute__((address_space(1))) void*)g,
        (__attribute__((address_space(3))) void*)l, 16, 0, 0);
}

// ---------------- Kernel 1: QKV projection (bf16 MFMA, f32 acc) ----------------
// grid (256, 3): x = 64-row tile of B*N, y = projection (0=Q,1=K,2=V).
// Q pre-scaled by 1/sqrt(128). V written in attn-LDS tile order:
//   VS[b][tile(128)][chunk(4)][d(128)][m8] bf16  (tile=32 m-rows, chunk=8 m's)
__global__ __launch_bounds__(256) void qkv_proj(
    const float* __restrict__ h,
    const float* __restrict__ Wq, const float* __restrict__ bq,
    const float* __restrict__ Wk, const float* __restrict__ bk,
    const float* __restrict__ Wv, const float* __restrict__ bv,
    unsigned short* __restrict__ qo, unsigned short* __restrict__ ko,
    unsigned short* __restrict__ vs, float qscale)
{
    __shared__ unsigned short h_lds[64 * 128];
    __shared__ unsigned short w_lds[128 * 128];

    const int tid = threadIdx.x;
    const int lane = tid & 63;
    const int wv = tid >> 6;
    const int l15 = lane & 15;
    const int lhi = lane >> 4;
    const int R0 = blockIdx.x * 64;
    const int proj = blockIdx.y;

    const float* W    = proj == 0 ? Wq : (proj == 1 ? Wk : Wv);
    const float* bias = proj == 0 ? bq : (proj == 1 ? bk : bv);
    const float scale = proj == 0 ? qscale : 1.0f;

    f32x4 acc[8];
#pragma unroll
    for (int i = 0; i < 8; ++i) acc[i] = f32x4{0.f, 0.f, 0.f, 0.f};

    for (int kc = 0; kc < 2; ++kc) {
        const int c0 = kc * 128;
        __syncthreads();
#pragma unroll
        for (int p = 0; p < 8; ++p) {
            int idx = p * 256 + tid;
            int row = idx >> 5;
            int seg = idx & 31;
            f32x4 hv = *reinterpret_cast<const f32x4*>(h + (size_t)(R0 + row) * NF + c0 + seg * 4);
            u16x4 hb;
            hb[0] = f2bf(hv[0]); hb[1] = f2bf(hv[1]); hb[2] = f2bf(hv[2]); hb[3] = f2bf(hv[3]);
            int byte = (row * 256 + seg * 8) ^ ((row & 7) << 4);
            *reinterpret_cast<u16x4*>(reinterpret_cast<char*>(h_lds) + byte) = hb;
        }
#pragma unroll
        for (int p = 0; p < 16; ++p) {
            int idx = p * 256 + tid;
            int row = idx >> 5;
            int seg = idx & 31;
            f32x4 wv4 = *reinterpret_cast<const f32x4*>(W + (size_t)row * NF + c0 + seg * 4);
            u16x4 wb;
            wb[0] = f2bf(wv4[0]); wb[1] = f2bf(wv4[1]); wb[2] = f2bf(wv4[2]); wb[3] = f2bf(wv4[3]);
            int byte = (row * 256 + seg * 8) ^ ((row & 7) << 4);
            *reinterpret_cast<u16x4*>(reinterpret_cast<char*>(w_lds) + byte) = wb;
        }
        __syncthreads();
        const int arow = 16 * wv + l15;
#pragma unroll
        for (int ks = 0; ks < 4; ++ks) {
            int k = ks * 32 + 8 * lhi;
            bf16x8 a = lds_read16(h_lds, (arow * 256 + k * 2) ^ ((arow & 7) << 4));
#pragma unroll
            for (int cs = 0; cs < 8; ++cs) {
                int d = 16 * cs + l15;
                bf16x8 b = lds_read16(w_lds, (d * 256 + k * 2) ^ ((d & 7) << 4));
                acc[cs] = __builtin_amdgcn_mfma_f32_16x16x32_bf16(a, b, acc[cs], 0, 0, 0);
            }
        }
    }
    if (proj < 2) {
        unsigned short* out = proj == 0 ? qo : ko;
#pragma unroll
        for (int cs = 0; cs < 8; ++cs) {
            int d = 16 * cs + l15;
            float bb = bias[d];
#pragma unroll
            for (int j = 0; j < 4; ++j) {
                int row = R0 + 16 * wv + 4 * lhi + j;
                out[(size_t)row * ND + d] = f2bf((acc[cs][j] + bb) * scale);
            }
        }
    } else {
        // V in attn-tile layout
        const int bb_ = R0 >> 12;
        const int nb_ = (R0 & (NN - 1)) + 16 * wv + 4 * lhi;
        const int pt = nb_ >> 5;
        const int ch = (nb_ >> 3) & 3;
        const int mm0 = nb_ & 7;
#pragma unroll
        for (int cs = 0; cs < 8; ++cs) {
            int d = 16 * cs + l15;
            float bb = bias[d];
            u16x4 o;
#pragma unroll
            for (int j = 0; j < 4; ++j) o[j] = f2bf(acc[cs][j] + bb);
            size_t idx = ((size_t)(bb_ * 128 + pt)) * 4096 + ch * 1024 + d * 8 + mm0;
            *reinterpret_cast<u16x4*>(vs + idx) = o;
        }
    }
}

// ---------------- Kernel 2: fused masked flash attention (KV-split) ----------------
// 256 threads = 4 waves; wave w owns q rows q0+16w..+15. KVB=32 double-buffered.
// LDS 36 KB -> 4 blocks/CU; VGPR ~120-130 -> 4 waves/SIMD = 16 waves/CU.
// NOTE: min-waves hint kept at 2 — (256,4) forced VGPR=64 and massive scratch
// spills (round 4: WRITE_SIZE 16->298 MB, MfmaUtil 8.5->3.9%).
__global__ __launch_bounds__(256, 2) void attn(
    const unsigned short* __restrict__ Q,   // [B*N,128] bf16, pre-scaled
    const unsigned short* __restrict__ K,   // [B*N,128] bf16
    const unsigned short* __restrict__ VS,  // tiled V (see proj)
    const int* __restrict__ adj,            // [B,N,N] i32
    float* __restrict__ out,                // split-0 partial O storage (and final out)
    float* __restrict__ opart1,             // splits 1.. partial O
    float* __restrict__ ml,                 // [nsplit][NR][2] f32 (m, l)
    int ntl)                                // tiles per split
{
    __shared__ unsigned short kA[KVB * 128], kB[KVB * 128];   // 8 KB each
    __shared__ unsigned short vA[4096], vB[4096];             // 8 KB each (tiled layout)
    __shared__ unsigned short p_lds[4 * 512];                 // per-wave 16x32 P tile

    const int tid = threadIdx.x;
    const int lane = tid & 63;
    const int w = tid >> 6;
    const int l15 = lane & 15;
    const int lhi = lane >> 4;

    // XCD-grouped decode: flat = s*512 + qt*8 + x ; combo = x + 8s -> (b, sp)
    const int flat = blockIdx.x;
    const int x = flat & 7;
    const int qt = (flat >> 3) & 63;
    const int s_ = flat >> 9;
    const int combo = x + 8 * s_;
    const int b = combo & 3;
    const int sp = combo >> 2;
    const int q0 = qt * QB;
    const size_t bN = (size_t)b * NN;
    const size_t abase = (size_t)b * NN * NN;
    const int ptbase = sp * ntl;

    auto stage = [&](unsigned short* kb, unsigned short* vb, int pt) {
        const int m0 = pt * KVB;
#pragma unroll
        for (int i = 0; i < 2; ++i) {
            int slot = w * 2 + i;                      // 0..7, 1 KB slots
            int row = slot * 4 + (lane >> 4);
            int pc = lane & 15;
            int lc = pc ^ (row & 7);
            gld_lds16(K + (bN + m0 + row) * ND + lc * 8, kb + slot * 512);
        }
        const unsigned short* vsrc = VS + ((size_t)(b * 128 + pt)) * 4096;
#pragma unroll
        for (int i = 0; i < 2; ++i) {
            int slot = w * 2 + i;
            gld_lds16(vsrc + slot * 512 + lane * 8, vb + slot * 512);
        }
    };
    auto adj_load = [&](int (&ar)[8], int pt) {
        const int m0 = pt * KVB;
#pragma unroll
        for (int ms = 0; ms < 2; ++ms)
#pragma unroll
            for (int j = 0; j < 4; ++j) {
                int r = 16 * w + 4 * lhi + j;
                int c = 16 * ms + l15;
                ar[ms * 4 + j] = adj[abase + (size_t)(q0 + r) * NN + m0 + c];
            }
    };

    int aregA[8], aregB[8];
    stage(kA, vA, ptbase);
    adj_load(aregA, ptbase);

    bf16x8 qf[4];
#pragma unroll
    for (int ks = 0; ks < 4; ++ks)
        qf[ks] = *reinterpret_cast<const bf16x8*>(Q + (bN + q0 + 16 * w + l15) * ND + ks * 32 + 8 * lhi);

    f32x4 acc_o[8];
#pragma unroll
    for (int i = 0; i < 8; ++i) acc_o[i] = f32x4{0.f, 0.f, 0.f, 0.f};
    float m_run[4], l_run[4];
#pragma unroll
    for (int j = 0; j < 4; ++j) { m_run[j] = -INFINITY; l_run[j] = 0.f; }

    auto body = [&](unsigned short* kc, unsigned short* vc, const int (&ac)[8],
                    unsigned short* kn, unsigned short* vn, int (&an)[8], int t) {
        int tn = (t + 1 < ntl) ? t + 1 : ntl - 1;
        stage(kn, vn, ptbase + tn);
        adj_load(an, ptbase + tn);
        // wait for CURRENT tile (12 per-wave VMEM ops/iter stay in flight)
        asm volatile("s_waitcnt vmcnt(12)" ::: "memory");
        __builtin_amdgcn_s_barrier();
        __builtin_amdgcn_sched_barrier(0);

        // ---- S = Q K^T  (32 m-cols = 2 subtiles)
        f32x4 s[2];
        __builtin_amdgcn_s_setprio(1);
#pragma unroll
        for (int ms = 0; ms < 2; ++ms) {
            s[ms] = f32x4{0.f, 0.f, 0.f, 0.f};
#pragma unroll
            for (int ks = 0; ks < 4; ++ks) {
                int mrow = 16 * ms + l15;
                bf16x8 bf = lds_read16(kc, (mrow * 256 + ks * 64 + lhi * 16) ^ ((mrow & 7) << 4));
                s[ms] = __builtin_amdgcn_mfma_f32_16x16x32_bf16(qf[ks], bf, s[ms], 0, 0, 0);
            }
        }
        __builtin_amdgcn_s_setprio(0);
        // ---- mask
#pragma unroll
        for (int ms = 0; ms < 2; ++ms)
#pragma unroll
            for (int j = 0; j < 4; ++j)
                if (ac[ms * 4 + j] == 0) s[ms][j] = -9e15f;
        // ---- online softmax
        float mnew[4], corr[4];
#pragma unroll
        for (int j = 0; j < 4; ++j) {
            float mx = fmaxf(s[0][j], s[1][j]);
#pragma unroll
            for (int off = 1; off < 16; off <<= 1)
                mx = fmaxf(mx, __shfl_xor(mx, off, 64));
            mnew[j] = fmaxf(m_run[j], mx);
            corr[j] = __expf(m_run[j] - mnew[j]);
            m_run[j] = mnew[j];
        }
        float rsum[4] = {0.f, 0.f, 0.f, 0.f};
        unsigned short pb[2][4];
#pragma unroll
        for (int ms = 0; ms < 2; ++ms)
#pragma unroll
            for (int j = 0; j < 4; ++j) {
                float p = __expf(s[ms][j] - mnew[j]);
                rsum[j] += p;
                pb[ms][j] = f2bf(p);
            }
#pragma unroll
        for (int j = 0; j < 4; ++j) {
            float rs = rsum[j];
#pragma unroll
            for (int off = 1; off < 16; off <<= 1)
                rs += __shfl_xor(rs, off, 64);
            l_run[j] = l_run[j] * corr[j] + rs;
#pragma unroll
            for (int ds = 0; ds < 8; ++ds) acc_o[ds][j] *= corr[j];
        }
        // ---- P -> per-wave LDS tile [16 q][32 m], 64B rows, (r&7)<<4 swizzle
#pragma unroll
        for (int ms = 0; ms < 2; ++ms)
#pragma unroll
            for (int j = 0; j < 4; ++j) {
                int r = 4 * lhi + j;
                int c = 16 * ms + l15;
                int byte = w * 1024 + ((r * 64 + c * 2) ^ ((r & 7) << 4));
                *reinterpret_cast<unsigned short*>(reinterpret_cast<char*>(p_lds) + byte) = pb[ms][j];
            }
        // ---- PV: acc_o += P @ V   (single 32-k window)
        {
            bf16x8 pa = lds_read16(p_lds, w * 1024 + ((l15 * 64 + lhi * 16) ^ ((l15 & 7) << 4)));
            __builtin_amdgcn_s_setprio(1);
#pragma unroll
            for (int ds = 0; ds < 8; ++ds) {
                int d = 16 * ds + l15;
                bf16x8 vbf = lds_read16(vc, lhi * 2048 + d * 16);
                acc_o[ds] = __builtin_amdgcn_mfma_f32_16x16x32_bf16(pa, vbf, acc_o[ds], 0, 0, 0);
            }
            __builtin_amdgcn_s_setprio(0);
        }
        asm volatile("s_waitcnt lgkmcnt(0)" ::: "memory");
        __builtin_amdgcn_sched_barrier(0);
        __builtin_amdgcn_s_barrier();
        __builtin_amdgcn_sched_barrier(0);
    };

    for (int t = 0; t < ntl; t += 2) {
        body(kA, vA, aregA, kB, vB, aregB, t);
        body(kB, vB, aregB, kA, vA, aregA, t + 1);
    }

    // ---- epilogue: store partial O (unnormalized) + (m, l)
    float* op = (sp == 0) ? out : (opart1 + (size_t)(sp - 1) * NR * ND);
#pragma unroll
    for (int ds = 0; ds < 8; ++ds) {
        int d = 16 * ds + l15;
#pragma unroll
        for (int j = 0; j < 4; ++j) {
            int row = q0 + 16 * w + 4 * lhi + j;
            op[(bN + row) * ND + d] = acc_o[ds][j];
        }
    }
    if (l15 == 0) {
#pragma unroll
        for (int j = 0; j < 4; ++j) {
            size_t gr = bN + q0 + 16 * w + 4 * lhi + j;
            float2 v2 = make_float2(m_run[j], l_run[j]);
            *reinterpret_cast<float2*>(ml + ((size_t)sp * NR + gr) * 2) = v2;
        }
    }
}

// ---------------- Kernel 3: merge the KV-splits (in-place on out) ----------------
__global__ __launch_bounds__(256) void merge_splits(
    float* __restrict__ out, const float* __restrict__ opart1,
    const float* __restrict__ ml, int nsplit)
{
    int idx = blockIdx.x * 256 + threadIdx.x;   // 0 .. NR*32-1
    int row = idx >> 5;
    int d4 = (idx & 31) * 4;
    float mmax = ml[(size_t)row * 2];
    for (int sp = 1; sp < nsplit; ++sp)
        mmax = fmaxf(mmax, ml[((size_t)sp * NR + row) * 2]);
    f32x4 o0 = *reinterpret_cast<const f32x4*>(out + (size_t)row * ND + d4);
    float w0 = __expf(ml[(size_t)row * 2] - mmax);
    float lsum = ml[(size_t)row * 2 + 1] * w0;
    f32x4 acc;
#pragma unroll
    for (int j = 0; j < 4; ++j) acc[j] = o0[j] * w0;
    for (int sp = 1; sp < nsplit; ++sp) {
        float m_s = ml[((size_t)sp * NR + row) * 2];
        float l_s = ml[((size_t)sp * NR + row) * 2 + 1];
        float ws_ = __expf(m_s - mmax);
        f32x4 os = *reinterpret_cast<const f32x4*>(opart1 + ((size_t)(sp - 1) * NR + row) * ND + d4);
#pragma unroll
        for (int j = 0; j < 4; ++j) acc[j] += os[j] * ws_;
        lsum += l_s * ws_;
    }
    float inv = 1.0f / lsum;
    f32x4 r;
#pragma unroll
    for (int j = 0; j < 4; ++j) r[j] = acc[j] * inv;
    *reinterpret_cast<f32x4*>(out + (size_t)row * ND + d4) = r;
}

extern "C" void kernel_launch(void* const* d_in, const int* in_sizes, int n_in,
                              void* d_out, int out_size, void* d_ws, size_t ws_size,
                              hipStream_t stream) {
    const float* h  = (const float*)d_in[0];
    const int* adj  = (const int*)d_in[1];
    const float* Wq = (const float*)d_in[2];
    const float* bq = (const float*)d_in[3];
    const float* Wk = (const float*)d_in[4];
    const float* bk = (const float*)d_in[5];
    const float* Wv = (const float*)d_in[6];
    const float* bv = (const float*)d_in[7];
    float* out = (float*)d_out;

    const size_t qkv_elems = (size_t)NB * NN * ND;      // 2,097,152 bf16 each
    unsigned short* qws  = (unsigned short*)d_ws;
    unsigned short* kws  = qws + qkv_elems;
    unsigned short* vsws = kws + qkv_elems;
    float* opart1 = (float*)(vsws + qkv_elems);

    // nsplit=4 needs 12.58MB (qkv) + 3*8.39MB (partials) + 0.52MB (ml)
    const size_t need4 = 3 * qkv_elems * 2 + 3 * (size_t)NR * ND * 4 + 4 * (size_t)NR * 2 * 4;
    const int nsplit = (ws_size >= need4) ? 4 : 2;
    float* mlws = opart1 + (size_t)(nsplit - 1) * NR * ND;
    const int ntl = (NN / KVB) / nsplit;                // 32 or 64

    const float qscale = 0.08838834764831845f;  // 1/sqrt(128)

    qkv_proj<<<dim3(NB * NN / 64, 3), 256, 0, stream>>>(
        h, Wq, bq, Wk, bk, Wv, bv, qws, kws, vsws, qscale);
    attn<<<dim3(NB * (NN / QB) * nsplit), 256, 0, stream>>>(
        qws, kws, vsws, adj, out, opart1, mlws, ntl);
    merge_splits<<<dim3(NR * 32 / 256), 256, 0, stream>>>(out, opart1, mlws, nsplit);
}